// Round 14
// baseline (102.587 us; speedup 1.0000x reference)
//
#include <hip/hip_runtime.h>

#define B_   64
#define H_   128
#define W_   2048
#define HW_  (H_ * W_)        // 262144
#define OH_  128
#define OW_  2048

typedef float nfloat4 __attribute__((ext_vector_type(4)));
typedef float f2v __attribute__((ext_vector_type(2), aligned(4)));

// OpenBLAS sgemm emulation — SkylakeX params (VERIFIED bit-exact in round 6):
//   SGEMM_DEFAULT_Q = 320; K = 262144 -> blocks 0..817 len 320,
//   blk 818: off 261760 len 192; blk 819: off 261952 len 192.
//   Per C element: single sequential FMA chain over k within each block;
//   cross-block C += S_blk ascending; + b_loc in fp32.
// !!! The per-(blk,b,j) fmaf sequence and the K2 fp32 replay are bit-locked —
// !!! optimizations may only change load mechanics / parallel mapping.
#define QBLK 320
#define NBLK 820

// d_out scratch layout (all fully overwritten by K2 at the end):
//   part: [0 .. 820*384)                  = 1.26 MB
//   wT  : [WT_OFF .. WT_OFF + 6*HW_)      = 6.3 MB  (wT[j][k] = w[k*6+j])
#define WT_OFF (1u << 21)   // 2,097,152 floats = 8 MB offset

__device__ __forceinline__ int blk_off(int blk) {
    if (blk <= 818) return blk * QBLK;    // 818*320 = 261760
    return 261952;                        // blk 819
}
__device__ __forceinline__ int blk_len(int blk) {
    return (blk < 818) ? 320 : 192;
}

// ---------------------------------------------------------------------------
// K0: transpose w (HW x 6) -> wT (6 x HW). Coalesced writes; strided reads
// (L2/L3-absorbed; 6.3 MB payload). ~2 us.
// ---------------------------------------------------------------------------
__global__ __launch_bounds__(256)
void st_wtrans(const float* __restrict__ w, float* __restrict__ wT)
{
    const int o = blockIdx.x * 256 + threadIdx.x;   // 0 .. 6*HW_-1
    const int j = o / HW_;
    const int k = o - j * HW_;
    wT[o] = w[(size_t)k * 6 + j];
}

// ---------------------------------------------------------------------------
// K1 (round-14): 820 blocks x 384 threads (6 waves). j = tid>>6 (wave-
// uniform), b = tid&63. 64-row x-panel in LDS (80 KB, single buffer,
// 2 blocks/CU), staged via global_load_lds w/ pre-swizzled global source
// (slot f4 of row r holds global unit f4^(r&7)); read side XORs back.
// w read from wT via readfirstlane-uniform pointer -> scalar (SMEM) loads:
// no LDS, no vector-VMEM, frees the LDS pipe (was 160 b128/thread, now 80).
// Chain = exact k-ascending fmaf sequence of the verified round-6 kernel.
// part layout: [kblk][b*6+j] (K1 store block-coalesced, K1b wave-coalesced).
// ---------------------------------------------------------------------------
__global__ __launch_bounds__(384)
void st_block_sums(const float* __restrict__ x, const float* __restrict__ wT,
                   float* __restrict__ part)
{
    __shared__ float4 xs4[64 * 80];      // 81920 B
    const int kblk = blockIdx.x;
    const int tid  = threadIdx.x;

    const int off = blk_off(kblk);
    const int len = blk_len(kblk);       // 320 or 192
    const int nt4 = len >> 2;            // 80 or 48 (both %8 == 0)

    const int widx = tid >> 6;           // wave 0..5
    const int lane = tid & 63;

    // stage x: slot idx = r*80 + f4 holds global float4-unit f4^(r&7) of
    // row r. Wave-uniform dest base + lane*16 (T21); per-lane global source.
#pragma unroll
    for (int i = 0; i < 14; ++i) {
        const int base = i * 384 + widx * 64;     // wave-uniform slot base
        if (base < 64 * 80) {                     // uniform per wave
            const int idx = base + lane;
            const int r   = idx / 80;
            const int f4  = idx % 80;
            if (f4 < nt4) {
                const int ug = f4 ^ (r & 7);
                const float* gp = x + (size_t)r * HW_ + off + ug * 4;
                __builtin_amdgcn_global_load_lds(
                    (const __attribute__((address_space(1))) unsigned int*)gp,
                    (__attribute__((address_space(3))) unsigned int*)&xs4[base],
                    16, 0, 0);
            }
        }
    }
    __syncthreads();   // drains global_load_lds (vmcnt)

    const int j  = widx;                 // 0..5, wave-uniform
    const int b  = lane;                 // 0..63
    const int wj = __builtin_amdgcn_readfirstlane(j);
    const int swz = b & 7;

    const float4* __restrict__ xr = xs4 + b * 80;
    const float4* __restrict__ wr4 =
        (const float4*)(wT + (size_t)wj * HW_ + off);   // SGPR base -> s_load

    float a = 0.f;
    if (nt4 == 80) {
#pragma unroll
        for (int t4 = 0; t4 < 80; ++t4) {
            const float4 xv = xr[t4 ^ swz];   // global unit t4 of row b
            const float4 wv = wr4[t4];        // w[k..k+3][j], scalar load
            a = fmaf(xv.x, wv.x, a);
            a = fmaf(xv.y, wv.y, a);
            a = fmaf(xv.z, wv.z, a);
            a = fmaf(xv.w, wv.w, a);
        }
    } else {
#pragma unroll
        for (int t4 = 0; t4 < 48; ++t4) {
            const float4 xv = xr[t4 ^ swz];
            const float4 wv = wr4[t4];
            a = fmaf(xv.x, wv.x, a);
            a = fmaf(xv.y, wv.y, a);
            a = fmaf(xv.z, wv.z, a);
            a = fmaf(xv.w, wv.w, a);
        }
    }

    part[(size_t)kblk * 384 + (size_t)b * 6 + j] = a;
}

// ---------------------------------------------------------------------------
// K1b: ordered cross-block accumulation (ascending), + b_loc in fp32.
// part[kblk][i]: wave reads 64 consecutive dwords per iteration (coalesced).
// ---------------------------------------------------------------------------
__global__ __launch_bounds__(64)
void st_theta_final(const float* __restrict__ part, const float* __restrict__ bl,
                    float* __restrict__ theta)
{
#pragma clang fp contract(off)
    const int i = blockIdx.x * 64 + threadIdx.x;   // 0..383
    const int j = i % 6;
    float acc = part[i];                           // S_0 (beta=0)
    for (int blk = 1; blk < NBLK; ++blk)
        acc = acc + part[(size_t)blk * 384 + i];
    theta[i] = acc + bl[j];
}

// ---------------------------------------------------------------------------
// K2 (round-14): bilinear sampler — faithful fp32 numpy replay downstream of
// theta (arithmetic IDENTICAL to round 6). Divergence-free loads: per pixel,
// base = min(x0c, W-2); one float2 per row; Ia/Ib/Ic/Id by cndmask.
//   interior        : base=x0c     -> Ia=v.x, Ic=v.y
//   left clamp  x0c=x1c=0    : base=0    -> Ia=v.x, Ic=v.x
//   right clamp x0c=x1c=2047 : base=2046 -> Ia=v.y, Ic=v.y
//   right edge  x0c=2046     : base=2046 -> Ia=v.x, Ic=v.y
// (pure bit-moves; values provably identical to the reference gathers)
// ---------------------------------------------------------------------------
__global__ __launch_bounds__(256)
void st_sample(const float* __restrict__ x, const float* __restrict__ theta,
               float* __restrict__ out)
{
#pragma clang fp contract(off)
    __shared__ float th[6];
    const int blk = blockIdx.x;
    const int b   = blk >> 8;          // 256 blocks per batch
    const int rem = blk & 255;
    const int yo  = rem >> 1;
    const int seg = rem & 1;

    if (threadIdx.x < 6) th[threadIdx.x] = theta[b * 6 + threadIdx.x];
    __syncthreads();

    const float t00 = th[0], t01 = th[1], t02 = th[2];
    const float t10 = th[3], t11 = th[4], t12 = th[5];

    const int xo0 = seg * 1024 + threadIdx.x * 4;
    const float* __restrict__ img = x + (size_t)b * HW_;
    const float yof = (float)yo;

    const float cx1 = t01 * yof;
    const float cy1 = t11 * yof;

    nfloat4 o;
#pragma unroll
    for (int i = 0; i < 4; ++i) {
        const float xof = (float)(xo0 + i);
        const float px  = t00 * xof;
        const float sx  = px + cx1;
        const float xq  = sx + t02;
        const float py  = t10 * xof;
        const float sy  = py + cy1;
        const float yq  = sy + t12;

        const int x0 = (int)floorf(xq);
        const int y0 = (int)floorf(yq);
        const int x0c = min(max(x0,     0), W_ - 1);
        const int x1c = min(max(x0 + 1, 0), W_ - 1);
        const int y0c = min(max(y0,     0), H_ - 1);
        const int y1c = min(max(y0 + 1, 0), H_ - 1);

        const int base = min(x0c, W_ - 2);
        const float* r0 = img + y0c * W_ + base;
        const float* r1 = img + y1c * W_ + base;
        const f2v v0 = *(const f2v*)r0;
        const f2v v1 = *(const f2v*)r1;

        const bool hiA = (x0c != base);   // only at right clamp
        const bool loC = (x1c == base);   // only at left clamp
        const float Ia = hiA ? v0.y : v0.x;
        const float Ic = loC ? v0.x : v0.y;
        const float Ib = hiA ? v1.y : v1.x;
        const float Id = loC ? v1.x : v1.y;

        const float x0f = (float)x0c, x1f = (float)x1c;
        const float y0f = (float)y0c, y1f = (float)y1c;

        const float gx = x1f - xq;
        const float fx = xq - x0f;
        const float gy = y1f - yq;
        const float fy = yq - y0f;

        const float wa = gx * gy;
        const float wb = gx * fy;
        const float wc = fx * gy;
        const float wd = fx * fy;

        const float pa = wa * Ia;
        const float pb = wb * Ib;
        const float s1 = pa + pb;
        const float pc = wc * Ic;
        const float s2 = s1 + pc;
        const float pd = wd * Id;
        o[i] = s2 + pd;
    }

    const size_t oidx = ((size_t)b * OH_ + yo) * OW_ + xo0;
    __builtin_nontemporal_store(o, (nfloat4*)(out + oidx));
}

extern "C" void kernel_launch(void* const* d_in, const int* in_sizes, int n_in,
                              void* d_out, int out_size, void* d_ws, size_t ws_size,
                              hipStream_t stream)
{
    const float* x  = (const float*)d_in[0];
    const float* w  = (const float*)d_in[1];
    const float* bl = (const float*)d_in[2];
    float* out = (float*)d_out;

    // d_out doubles as scratch (part @0, wT @WT_OFF), fully consumed by
    // st_theta_final / st_block_sums before st_sample overwrites everything.
    float* part  = (float*)d_out;
    float* wT    = (float*)d_out + WT_OFF;
    float* theta = (float*)d_ws;    // 384 floats

    st_wtrans<<<(6 * HW_) / 256, 256, 0, stream>>>(w, wT);
    st_block_sums<<<NBLK, 384, 0, stream>>>(x, wT, part);
    st_theta_final<<<6, 64, 0, stream>>>(part, bl, theta);
    st_sample<<<B_ * OH_ * 2, 256, 0, stream>>>(x, theta, out);
}

// Round 15
// 90.302 us; speedup vs baseline: 1.1360x; 1.1360x over previous
//
#include <hip/hip_runtime.h>

#define B_   64
#define H_   128
#define W_   2048
#define HW_  (H_ * W_)        // 262144
#define OH_  128
#define OW_  2048

typedef float nfloat4 __attribute__((ext_vector_type(4)));
typedef float f2v __attribute__((ext_vector_type(2), aligned(4)));

// OpenBLAS sgemm emulation — SkylakeX params (VERIFIED bit-exact in round 6):
//   SGEMM_DEFAULT_Q = 320; K = 262144 -> blocks 0..817 len 320,
//   blk 818: off 261760 len 192; blk 819: off 261952 len 192.
//   Per C element: single sequential FMA chain over k within each block;
//   cross-block C += S_blk ascending; + b_loc in fp32.
// !!! The per-(blk,b,j) fmaf sequence and the K2 fp32 replay are bit-locked —
// !!! optimizations may only change load mechanics / parallel mapping.
#define QBLK 320
#define NBLK 820

// d_out scratch layout (fully overwritten by K2 at the end):
//   part: [0 .. 820*384)               = 1.26 MB
//   wT  : [WT_OFF .. WT_OFF + 6*HW_)   = 6.3 MB  (wT[j][k] = w[k*6+j])
#define WT_OFF (1u << 21)   // 8 MB offset

__device__ __forceinline__ int blk_off(int blk) {
    if (blk <= 818) return blk * QBLK;    // 818*320 = 261760
    return 261952;                        // blk 819
}
__device__ __forceinline__ int blk_len(int blk) {
    return (blk < 818) ? 320 : 192;
}
__device__ __forceinline__ int swz2(int r) { return (r ^ (r >> 3)) & 7; }

// ---------------------------------------------------------------------------
// K0 (round-15): w transpose via LDS. Block = 64 w-rows (384 floats).
// Reads fully coalesced; writes 6 segments of 64 consecutive floats.
// (round-14's strided 1-float/thread version cost ~15 us)
// ---------------------------------------------------------------------------
__global__ __launch_bounds__(384)
void st_wtrans(const float* __restrict__ w, float* __restrict__ wT)
{
    __shared__ float t[384];
    const int g   = blockIdx.x;          // 0 .. HW_/64-1
    const int tid = threadIdx.x;
    t[tid] = w[(size_t)g * 384 + tid];
    __syncthreads();
    const int j  = tid >> 6;             // 0..5
    const int kk = tid & 63;
    wT[(size_t)j * HW_ + g * 64 + kk] = t[kk * 6 + j];
}

// ---------------------------------------------------------------------------
// K1 (round-15): 1640 blocks x 192 threads (3 waves); block = (kblk, 32-row
// half); thread = (j = tid>>5, b = tid&31).
//  - x staged via global_load_lds w=16, pre-swizzled global source: slot f4
//    of row r holds global unit f4^swz2(r), swz2 = (r^(r>>3))&7 (kills the
//    4-way {b,b+8,b+16,b+24} bank classes of the plain r&7 swizzle).
//  - w from wT via wave-shared vector GLOBAL load (2 distinct addrs/wave ->
//    1-2 line txns, L1-hot, vmcnt-tracked: does NOT serialize ds_read's
//    counted lgkmcnt — round-14's SMEM/lgkm mixing is gone).
//  - LDS = 40 KB x-panel only -> 4 blocks/CU (12 waves/CU): staging of one
//    block overlaps compute of the others.
// Chain = exact k-ascending fmaf sequence of the verified round-6 kernel.
// part layout: [kblk][b*6+j] (K1 store block-coalesced, K1b wave-coalesced).
// ---------------------------------------------------------------------------
__global__ __launch_bounds__(192)
void st_block_sums(const float* __restrict__ x, const float* __restrict__ wT,
                   float* __restrict__ part)
{
    __shared__ float4 xs4[32 * 80];      // 40960 B -> 4 blocks/CU
    const int kblk = blockIdx.x >> 1;
    const int half = blockIdx.x & 1;
    const int tid  = threadIdx.x;

    const int off = blk_off(kblk);
    const int len = blk_len(kblk);       // 320 or 192
    const int nt4 = len >> 2;            // 80 or 48 (both %8 == 0)
    const int b0  = half * 32;

    const int widx = tid >> 6;           // wave 0..2
    const int lane = tid & 63;

    // stage x: slot r*80+f4 holds global unit f4^swz2(r) of row b0+r.
    // Wave-uniform LDS dest base + lane*16 (T21); per-lane global source.
#pragma unroll
    for (int i = 0; i < 14; ++i) {
        const int base = i * 192 + widx * 64;     // wave-uniform slot base
        if (base < 32 * 80) {                     // uniform per wave
            const int idx = base + lane;
            const int r   = idx / 80;
            const int f4  = idx % 80;
            if (f4 < nt4) {
                const int ug = f4 ^ swz2(r);
                const float* gp = x + (size_t)(b0 + r) * HW_ + off + ug * 4;
                __builtin_amdgcn_global_load_lds(
                    (const __attribute__((address_space(1))) unsigned int*)gp,
                    (__attribute__((address_space(3))) unsigned int*)&xs4[base],
                    16, 0, 0);
            }
        }
    }
    __syncthreads();   // drains global_load_lds (vmcnt)

    const int j = tid >> 5;              // 0..5 (2 j per wave)
    const int b = tid & 31;              // row within half
    const int sz = swz2(b);

    const float4* __restrict__ xr = xs4 + b * 80;
    const float4* __restrict__ wr4 =
        (const float4*)(wT + (size_t)j * HW_ + off);   // shared by 32 lanes

    float a = 0.f;
    if (nt4 == 80) {
#pragma unroll
        for (int t4 = 0; t4 < 80; ++t4) {
            const float4 xv = xr[t4 ^ sz];    // global unit t4 of row b
            const float4 wv = wr4[t4];        // wT[j][k..k+3], 2 lines/wave
            a = fmaf(xv.x, wv.x, a);
            a = fmaf(xv.y, wv.y, a);
            a = fmaf(xv.z, wv.z, a);
            a = fmaf(xv.w, wv.w, a);
        }
    } else {
#pragma unroll
        for (int t4 = 0; t4 < 48; ++t4) {
            const float4 xv = xr[t4 ^ sz];
            const float4 wv = wr4[t4];
            a = fmaf(xv.x, wv.x, a);
            a = fmaf(xv.y, wv.y, a);
            a = fmaf(xv.z, wv.z, a);
            a = fmaf(xv.w, wv.w, a);
        }
    }

    part[(size_t)kblk * 384 + (size_t)(b0 + b) * 6 + j] = a;
}

// ---------------------------------------------------------------------------
// K1b: ordered cross-block accumulation (ascending), + b_loc in fp32.
// part[kblk][i]: wave reads 64 consecutive dwords per iteration (coalesced).
// ---------------------------------------------------------------------------
__global__ __launch_bounds__(64)
void st_theta_final(const float* __restrict__ part, const float* __restrict__ bl,
                    float* __restrict__ theta)
{
#pragma clang fp contract(off)
    const int i = blockIdx.x * 64 + threadIdx.x;   // 0..383
    const int j = i % 6;
    float acc = part[i];                           // S_0 (beta=0)
    for (int blk = 1; blk < NBLK; ++blk)
        acc = acc + part[(size_t)blk * 384 + i];
    theta[i] = acc + bl[j];
}

// ---------------------------------------------------------------------------
// K2: bilinear sampler — faithful fp32 numpy replay downstream of theta
// (arithmetic IDENTICAL to round 6). Divergence-free loads (round-14,
// verified): base = min(x0c, W-2); one float2 per row; Ia/Ib/Ic/Id cndmask.
// ---------------------------------------------------------------------------
__global__ __launch_bounds__(256)
void st_sample(const float* __restrict__ x, const float* __restrict__ theta,
               float* __restrict__ out)
{
#pragma clang fp contract(off)
    __shared__ float th[6];
    const int blk = blockIdx.x;
    const int b   = blk >> 8;          // 256 blocks per batch
    const int rem = blk & 255;
    const int yo  = rem >> 1;
    const int seg = rem & 1;

    if (threadIdx.x < 6) th[threadIdx.x] = theta[b * 6 + threadIdx.x];
    __syncthreads();

    const float t00 = th[0], t01 = th[1], t02 = th[2];
    const float t10 = th[3], t11 = th[4], t12 = th[5];

    const int xo0 = seg * 1024 + threadIdx.x * 4;
    const float* __restrict__ img = x + (size_t)b * HW_;
    const float yof = (float)yo;

    const float cx1 = t01 * yof;
    const float cy1 = t11 * yof;

    nfloat4 o;
#pragma unroll
    for (int i = 0; i < 4; ++i) {
        const float xof = (float)(xo0 + i);
        const float px  = t00 * xof;
        const float sx  = px + cx1;
        const float xq  = sx + t02;
        const float py  = t10 * xof;
        const float sy  = py + cy1;
        const float yq  = sy + t12;

        const int x0 = (int)floorf(xq);
        const int y0 = (int)floorf(yq);
        const int x0c = min(max(x0,     0), W_ - 1);
        const int x1c = min(max(x0 + 1, 0), W_ - 1);
        const int y0c = min(max(y0,     0), H_ - 1);
        const int y1c = min(max(y0 + 1, 0), H_ - 1);

        const int base = min(x0c, W_ - 2);
        const float* r0 = img + y0c * W_ + base;
        const float* r1 = img + y1c * W_ + base;
        const f2v v0 = *(const f2v*)r0;
        const f2v v1 = *(const f2v*)r1;

        const bool hiA = (x0c != base);   // only at right clamp
        const bool loC = (x1c == base);   // only at left clamp
        const float Ia = hiA ? v0.y : v0.x;
        const float Ic = loC ? v0.x : v0.y;
        const float Ib = hiA ? v1.y : v1.x;
        const float Id = loC ? v1.x : v1.y;

        const float x0f = (float)x0c, x1f = (float)x1c;
        const float y0f = (float)y0c, y1f = (float)y1c;

        const float gx = x1f - xq;
        const float fx = xq - x0f;
        const float gy = y1f - yq;
        const float fy = yq - y0f;

        const float wa = gx * gy;
        const float wb = gx * fy;
        const float wc = fx * gy;
        const float wd = fx * fy;

        const float pa = wa * Ia;
        const float pb = wb * Ib;
        const float s1 = pa + pb;
        const float pc = wc * Ic;
        const float s2 = s1 + pc;
        const float pd = wd * Id;
        o[i] = s2 + pd;
    }

    const size_t oidx = ((size_t)b * OH_ + yo) * OW_ + xo0;
    __builtin_nontemporal_store(o, (nfloat4*)(out + oidx));
}

extern "C" void kernel_launch(void* const* d_in, const int* in_sizes, int n_in,
                              void* d_out, int out_size, void* d_ws, size_t ws_size,
                              hipStream_t stream)
{
    const float* x  = (const float*)d_in[0];
    const float* w  = (const float*)d_in[1];
    const float* bl = (const float*)d_in[2];
    float* out = (float*)d_out;

    // d_out doubles as scratch (part @0, wT @WT_OFF), fully consumed before
    // st_sample overwrites everything.
    float* part  = (float*)d_out;
    float* wT    = (float*)d_out + WT_OFF;
    float* theta = (float*)d_ws;    // 384 floats

    st_wtrans<<<HW_ / 64, 384, 0, stream>>>(w, wT);
    st_block_sums<<<NBLK * 2, 192, 0, stream>>>(x, wT, part);
    st_theta_final<<<6, 64, 0, stream>>>(part, bl, theta);
    st_sample<<<B_ * OH_ * 2, 256, 0, stream>>>(x, theta, out);
}

// Round 16
// 88.567 us; speedup vs baseline: 1.1583x; 1.0196x over previous
//
#include <hip/hip_runtime.h>

#define B_   64
#define H_   128
#define W_   2048
#define HW_  (H_ * W_)        // 262144
#define OH_  128
#define OW_  2048

typedef float nfloat4 __attribute__((ext_vector_type(4)));
typedef float f2v __attribute__((ext_vector_type(2), aligned(4)));

// OpenBLAS sgemm emulation — SkylakeX params (VERIFIED bit-exact in round 6):
//   SGEMM_DEFAULT_Q = 320; K = 262144 -> blocks 0..817 len 320,
//   blk 818: off 261760 len 192; blk 819: off 261952 len 192.
//   Per C element: single sequential FMA chain over k within each block;
//   cross-block C += S_blk ascending; + b_loc in fp32.
// !!! The per-(blk,b,j) fmaf sequence and the K2 fp32 replay are bit-locked —
// !!! optimizations may only change load mechanics / parallel mapping.
#define QBLK 320
#define NBLK 820

// d_out scratch layout (fully overwritten by K2 at the end):
//   part: [0 .. 820*384)               = 1.26 MB
//   wT  : [WT_OFF .. WT_OFF + 6*HW_)   = 6.3 MB  (wT[j][k] = w[k*6+j])
#define WT_OFF (1u << 21)   // 8 MB offset

__device__ __forceinline__ int blk_off(int blk) {
    if (blk <= 818) return blk * QBLK;    // 818*320 = 261760
    return 261952;                        // blk 819
}
__device__ __forceinline__ int blk_len(int blk) {
    return (blk < 818) ? 320 : 192;
}
__device__ __forceinline__ int swz2(int r) { return (r ^ (r >> 3)) & 7; }

// ---------------------------------------------------------------------------
// K0: w transpose via LDS (round-15, ~2.5 us). Reads fully coalesced;
// writes 6 segments of 64 consecutive floats.
// ---------------------------------------------------------------------------
__global__ __launch_bounds__(384)
void st_wtrans(const float* __restrict__ w, float* __restrict__ wT)
{
    __shared__ float t[384];
    const int g   = blockIdx.x;          // 0 .. HW_/64-1
    const int tid = threadIdx.x;
    t[tid] = w[(size_t)g * 384 + tid];
    __syncthreads();
    const int j  = tid >> 6;             // 0..5
    const int kk = tid & 63;
    wT[(size_t)j * HW_ + g * 64 + kk] = t[kk * 6 + j];
}

// ---------------------------------------------------------------------------
// K1 (round-15 structure, unchanged — best measured variant, ~38-40 us):
// 1640 blocks x 192 threads; block = (kblk, 32-row half); thread = (j, b).
// x staged via global_load_lds w=16 w/ pre-swizzled source (swz2); w from wT
// via wave-shared vector global loads (vmcnt, no lgkm mixing); 40 KB LDS ->
// 4 blocks/CU. Chain = exact k-ascending fmaf sequence.
// part layout: [kblk][b*6+j].
// ---------------------------------------------------------------------------
__global__ __launch_bounds__(192)
void st_block_sums(const float* __restrict__ x, const float* __restrict__ wT,
                   float* __restrict__ part)
{
    __shared__ float4 xs4[32 * 80];      // 40960 B
    const int kblk = blockIdx.x >> 1;
    const int half = blockIdx.x & 1;
    const int tid  = threadIdx.x;

    const int off = blk_off(kblk);
    const int len = blk_len(kblk);       // 320 or 192
    const int nt4 = len >> 2;            // 80 or 48 (both %8 == 0)
    const int b0  = half * 32;

    const int widx = tid >> 6;           // wave 0..2
    const int lane = tid & 63;

#pragma unroll
    for (int i = 0; i < 14; ++i) {
        const int base = i * 192 + widx * 64;     // wave-uniform slot base
        if (base < 32 * 80) {                     // uniform per wave
            const int idx = base + lane;
            const int r   = idx / 80;
            const int f4  = idx % 80;
            if (f4 < nt4) {
                const int ug = f4 ^ swz2(r);
                const float* gp = x + (size_t)(b0 + r) * HW_ + off + ug * 4;
                __builtin_amdgcn_global_load_lds(
                    (const __attribute__((address_space(1))) unsigned int*)gp,
                    (__attribute__((address_space(3))) unsigned int*)&xs4[base],
                    16, 0, 0);
            }
        }
    }
    __syncthreads();   // drains global_load_lds (vmcnt)

    const int j = tid >> 5;              // 0..5 (2 j per wave)
    const int b = tid & 31;              // row within half
    const int sz = swz2(b);

    const float4* __restrict__ xr = xs4 + b * 80;
    const float4* __restrict__ wr4 =
        (const float4*)(wT + (size_t)j * HW_ + off);   // shared by 32 lanes

    float a = 0.f;
    if (nt4 == 80) {
#pragma unroll
        for (int t4 = 0; t4 < 80; ++t4) {
            const float4 xv = xr[t4 ^ sz];
            const float4 wv = wr4[t4];
            a = fmaf(xv.x, wv.x, a);
            a = fmaf(xv.y, wv.y, a);
            a = fmaf(xv.z, wv.z, a);
            a = fmaf(xv.w, wv.w, a);
        }
    } else {
#pragma unroll
        for (int t4 = 0; t4 < 48; ++t4) {
            const float4 xv = xr[t4 ^ sz];
            const float4 wv = wr4[t4];
            a = fmaf(xv.x, wv.x, a);
            a = fmaf(xv.y, wv.y, a);
            a = fmaf(xv.z, wv.z, a);
            a = fmaf(xv.w, wv.w, a);
        }
    }

    part[(size_t)kblk * 384 + (size_t)(b0 + b) * 6 + j] = a;
}

// ---------------------------------------------------------------------------
// K1b: ordered cross-block accumulation (ascending), + b_loc in fp32.
// ---------------------------------------------------------------------------
__global__ __launch_bounds__(64)
void st_theta_final(const float* __restrict__ part, const float* __restrict__ bl,
                    float* __restrict__ theta)
{
#pragma clang fp contract(off)
    const int i = blockIdx.x * 64 + threadIdx.x;   // 0..383
    const int j = i % 6;
    float acc = part[i];                           // S_0 (beta=0)
    for (int blk = 1; blk < NBLK; ++blk)
        acc = acc + part[(size_t)blk * 384 + i];
    theta[i] = acc + bl[j];
}

// ---------------------------------------------------------------------------
// K2 (round-16): bilinear sampler — faithful fp32 numpy replay (values
// IDENTICAL to round 6; VALU-trimmed). Clip in FLOAT domain via v_med3_f32:
//   x0f = med3(floor(xq),0,2047) == (float)x0c   (integers exact in fp32)
//   x1f = med3(floor(xq)+1,0,2047) == (float)x1c
//   basef = min(x0f, 2046); hiA <=> x0f==2047; loC <=> x1f==basef
// (case-verified: interior / left-clamp / right-edge / right-clamp)
// Only 3 int cvts (base, y0c, y1c) survive, for addressing via mad_u32_u24.
// Weight/blend sequence unchanged (contract off, numpy order).
// ---------------------------------------------------------------------------
__global__ __launch_bounds__(256)
void st_sample(const float* __restrict__ x, const float* __restrict__ theta,
               float* __restrict__ out)
{
#pragma clang fp contract(off)
    __shared__ float th[6];
    const int blk = blockIdx.x;
    const int b   = blk >> 8;          // 256 blocks per batch
    const int rem = blk & 255;
    const int yo  = rem >> 1;
    const int seg = rem & 1;

    if (threadIdx.x < 6) th[threadIdx.x] = theta[b * 6 + threadIdx.x];
    __syncthreads();

    const float t00 = th[0], t01 = th[1], t02 = th[2];
    const float t10 = th[3], t11 = th[4], t12 = th[5];

    const int xo0 = seg * 1024 + threadIdx.x * 4;
    const float* __restrict__ img = x + (size_t)b * HW_;
    const float yof = (float)yo;

    const float cx1 = t01 * yof;
    const float cy1 = t11 * yof;

    nfloat4 o;
#pragma unroll
    for (int i = 0; i < 4; ++i) {
        const float xof = (float)(xo0 + i);
        const float px  = t00 * xof;
        const float sx  = px + cx1;
        const float xq  = sx + t02;
        const float py  = t10 * xof;
        const float sy  = py + cy1;
        const float yq  = sy + t12;

        const float xf0 = floorf(xq);
        const float yf0 = floorf(yq);

        const float x0f = __builtin_amdgcn_fmed3f(xf0,        0.f, 2047.f);
        const float x1f = __builtin_amdgcn_fmed3f(xf0 + 1.0f, 0.f, 2047.f);
        const float y0f = __builtin_amdgcn_fmed3f(yf0,        0.f,  127.f);
        const float y1f = __builtin_amdgcn_fmed3f(yf0 + 1.0f, 0.f,  127.f);

        const float basef = fminf(x0f, 2046.0f);
        const int base_i = (int)basef;
        const int y0c    = (int)y0f;
        const int y1c    = (int)y1f;

        const f2v v0 = *(const f2v*)(img + y0c * W_ + base_i);
        const f2v v1 = *(const f2v*)(img + y1c * W_ + base_i);

        const bool hiA = (x0f == 2047.0f);   // right clamp
        const bool loC = (x1f == basef);     // left clamp
        const float Ia = hiA ? v0.y : v0.x;
        const float Ic = loC ? v0.x : v0.y;
        const float Ib = hiA ? v1.y : v1.x;
        const float Id = loC ? v1.x : v1.y;

        const float gx = x1f - xq;
        const float fx = xq - x0f;
        const float gy = y1f - yq;
        const float fy = yq - y0f;

        const float wa = gx * gy;
        const float wb = gx * fy;
        const float wc = fx * gy;
        const float wd = fx * fy;

        const float pa = wa * Ia;
        const float pb = wb * Ib;
        const float s1 = pa + pb;
        const float pc = wc * Ic;
        const float s2 = s1 + pc;
        const float pd = wd * Id;
        o[i] = s2 + pd;
    }

    const size_t oidx = ((size_t)b * OH_ + yo) * OW_ + xo0;
    __builtin_nontemporal_store(o, (nfloat4*)(out + oidx));
}

extern "C" void kernel_launch(void* const* d_in, const int* in_sizes, int n_in,
                              void* d_out, int out_size, void* d_ws, size_t ws_size,
                              hipStream_t stream)
{
    const float* x  = (const float*)d_in[0];
    const float* w  = (const float*)d_in[1];
    const float* bl = (const float*)d_in[2];
    float* out = (float*)d_out;

    float* part  = (float*)d_out;
    float* wT    = (float*)d_out + WT_OFF;
    float* theta = (float*)d_ws;    // 384 floats

    st_wtrans<<<HW_ / 64, 384, 0, stream>>>(w, wT);
    st_block_sums<<<NBLK * 2, 192, 0, stream>>>(x, wT, part);
    st_theta_final<<<6, 64, 0, stream>>>(part, bl, theta);
    st_sample<<<B_ * OH_ * 2, 256, 0, stream>>>(x, theta, out);
}

// Round 17
// 69.209 us; speedup vs baseline: 1.4823x; 1.2797x over previous
//
#include <hip/hip_runtime.h>

#define B_   64
#define H_   128
#define W_   2048
#define HW_  (H_ * W_)        // 262144
#define OH_  128
#define OW_  2048

typedef float nfloat4 __attribute__((ext_vector_type(4)));
typedef float f2v __attribute__((ext_vector_type(2), aligned(4)));

// OpenBLAS sgemm emulation — SkylakeX params (VERIFIED bit-exact in round 6):
//   SGEMM_DEFAULT_Q = 320; K = 262144 -> blocks 0..817 len 320,
//   blk 818: off 261760 len 192; blk 819: off 261952 len 192.
//   Per C element: single sequential FMA chain over k within each block;
//   cross-block C += S_blk ascending; + b_loc in fp32.
// !!! The per-(blk,b,j) fmaf sequence and the K2 fp32 replay are bit-locked —
// !!! optimizations may only change load mechanics / parallel mapping.
#define QBLK 320
#define NBLK 820

__device__ __forceinline__ int blk_off(int blk) {
    if (blk <= 818) return blk * QBLK;    // 818*320 = 261760
    return 261952;                        // blk 819
}
__device__ __forceinline__ int blk_len(int blk) {
    return (blk < 818) ? 320 : 192;
}

// ---------------------------------------------------------------------------
// K1 (round-17): r13 structure (x via global_load_lds, w via LDS broadcast)
// with STRIDE-81 row padding instead of XOR swizzle.
//   81 = 1 mod 8  =>  lane b reading unit t4 hits bank-group (b+t4)&7:
//   4 distinct addresses + 1 broadcast pair per group = conflict-free
//   (r13's swz left 8 lanes/group: 1.57M conflict cycles).
//   Linear slot map: s -> row s/81, unit s%81; pad unit 80 never read, so
//   global_load_lds needs NO source swizzle.
// 1640 blocks x 192 thr (3 waves); block = (kblk, 32-row half);
// thread = (j = tid>>5, b = tid&31). LDS = 41472 + 7680 = 48.0 KB -> 3/CU.
// Chain = exact k-ascending fmaf sequence of the verified round-6 kernel.
// part layout: [kblk][b*6+j].
// ---------------------------------------------------------------------------
#define XSTR 81
__global__ __launch_bounds__(192)
void st_block_sums(const float* __restrict__ x, const float* __restrict__ w,
                   float* __restrict__ part)
{
    __shared__ float4 xs4[32 * XSTR];    // 41472 B
    __shared__ float  wt[6 * QBLK];      //  7680 B  (48.0 KB total)
    const int kblk = blockIdx.x >> 1;
    const int half = blockIdx.x & 1;
    const int tid  = threadIdx.x;

    const int off = blk_off(kblk);
    const int len = blk_len(kblk);       // 320 or 192
    const int nt4 = len >> 2;            // 80 or 48
    const int b0  = half * 32;

    const int widx = tid >> 6;           // wave 0..2
    const int lane = tid & 63;

    // x staging: slot s holds global unit (s%81, clamped into row) of row
    // s/81. Wave-uniform LDS dest base + lane*16; per-lane source; EXEC-
    // masked tail. Pad slots (unit 80 / units >= nt4) load unit 0: never read.
#pragma unroll
    for (int i = 0; i < 14; ++i) {
        const int base = i * 192 + widx * 64;     // wave-uniform slot base
        if (base < 32 * XSTR) {                   // uniform per wave
            const int idx = base + lane;
            if (idx < 32 * XSTR) {                // EXEC mask (last chunk)
                const int r  = idx / XSTR;
                const int f4 = idx % XSTR;
                const int ug = (f4 < nt4) ? f4 : 0;   // pad -> harmless src
                const float* gp = x + (size_t)(b0 + r) * HW_ + off + ug * 4;
                __builtin_amdgcn_global_load_lds(
                    (const __attribute__((address_space(1))) unsigned int*)gp,
                    (__attribute__((address_space(3))) unsigned int*)&xs4[base],
                    16, 0, 0);
            }
        }
    }

    // w staging: batched regs -> transposed LDS wt[j][k]
    float wreg[10];
#pragma unroll
    for (int i = 0; i < 10; ++i) {
        const int e = tid + i * 192;
        wreg[i] = (e < 6 * len) ? w[(size_t)off * 6 + e] : 0.f;
    }
#pragma unroll
    for (int i = 0; i < 10; ++i) {
        const int e = tid + i * 192;
        if (e < 6 * len) wt[(e % 6) * QBLK + (e / 6)] = wreg[i];
    }
    __syncthreads();   // drains global_load_lds (vmcnt) + ds_writes

    const int j = tid >> 5;              // 0..5 (2 j per wave)
    const int b = tid & 31;              // row within half

    const float4* __restrict__ xr = xs4 + b * XSTR;
    const float*  __restrict__ wr = wt + j * QBLK;

    float a = 0.f;
    if (nt4 == 80) {
#pragma unroll
        for (int t4 = 0; t4 < 80; ++t4) {
            const float4 xv = xr[t4];                          // conflict-free
            const float4 wv = *(const float4*)(wr + t4 * 4);   // broadcast
            a = fmaf(xv.x, wv.x, a);
            a = fmaf(xv.y, wv.y, a);
            a = fmaf(xv.z, wv.z, a);
            a = fmaf(xv.w, wv.w, a);
        }
    } else {
#pragma unroll
        for (int t4 = 0; t4 < 48; ++t4) {
            const float4 xv = xr[t4];
            const float4 wv = *(const float4*)(wr + t4 * 4);
            a = fmaf(xv.x, wv.x, a);
            a = fmaf(xv.y, wv.y, a);
            a = fmaf(xv.z, wv.z, a);
            a = fmaf(xv.w, wv.w, a);
        }
    }

    part[(size_t)kblk * 384 + (size_t)(b0 + b) * 6 + j] = a;
}

// ---------------------------------------------------------------------------
// K1b (round-17): ordered cross-block accumulation, latency-batched.
// 820 = 12*64 + 52: load 64 (or 52) independent values into registers
// (compile-time sizes -> no spills, deep MLP), THEN do the ordered adds.
// Add order identical to the sequential version -> bit-exact.
// ---------------------------------------------------------------------------
__global__ __launch_bounds__(64)
void st_theta_final(const float* __restrict__ part, const float* __restrict__ bl,
                    float* __restrict__ theta)
{
#pragma clang fp contract(off)
    const int i = blockIdx.x * 64 + threadIdx.x;   // 0..383
    const int j = i % 6;
    const float* __restrict__ p = part + i;        // stride 384 per kblk

    float acc;
    {
        float r[64];
#pragma unroll
        for (int u = 0; u < 64; ++u) r[u] = p[(size_t)u * 384];
        acc = r[0];
#pragma unroll
        for (int u = 1; u < 64; ++u) acc = acc + r[u];
    }
    for (int base = 64; base < 768; base += 64) {
        float r[64];
#pragma unroll
        for (int u = 0; u < 64; ++u) r[u] = p[(size_t)(base + u) * 384];
#pragma unroll
        for (int u = 0; u < 64; ++u) acc = acc + r[u];
    }
    {
        float r[52];
#pragma unroll
        for (int u = 0; u < 52; ++u) r[u] = p[(size_t)(768 + u) * 384];
#pragma unroll
        for (int u = 0; u < 52; ++u) acc = acc + r[u];
    }
    theta[i] = acc + bl[j];
}

// ---------------------------------------------------------------------------
// K2 (round-16, unchanged): bilinear sampler — faithful fp32 numpy replay.
// Float-domain clip via v_med3_f32; divergence-free float2 loads + cndmask.
// ---------------------------------------------------------------------------
__global__ __launch_bounds__(256)
void st_sample(const float* __restrict__ x, const float* __restrict__ theta,
               float* __restrict__ out)
{
#pragma clang fp contract(off)
    __shared__ float th[6];
    const int blk = blockIdx.x;
    const int b   = blk >> 8;          // 256 blocks per batch
    const int rem = blk & 255;
    const int yo  = rem >> 1;
    const int seg = rem & 1;

    if (threadIdx.x < 6) th[threadIdx.x] = theta[b * 6 + threadIdx.x];
    __syncthreads();

    const float t00 = th[0], t01 = th[1], t02 = th[2];
    const float t10 = th[3], t11 = th[4], t12 = th[5];

    const int xo0 = seg * 1024 + threadIdx.x * 4;
    const float* __restrict__ img = x + (size_t)b * HW_;
    const float yof = (float)yo;

    const float cx1 = t01 * yof;
    const float cy1 = t11 * yof;

    nfloat4 o;
#pragma unroll
    for (int i = 0; i < 4; ++i) {
        const float xof = (float)(xo0 + i);
        const float px  = t00 * xof;
        const float sx  = px + cx1;
        const float xq  = sx + t02;
        const float py  = t10 * xof;
        const float sy  = py + cy1;
        const float yq  = sy + t12;

        const float xf0 = floorf(xq);
        const float yf0 = floorf(yq);

        const float x0f = __builtin_amdgcn_fmed3f(xf0,        0.f, 2047.f);
        const float x1f = __builtin_amdgcn_fmed3f(xf0 + 1.0f, 0.f, 2047.f);
        const float y0f = __builtin_amdgcn_fmed3f(yf0,        0.f,  127.f);
        const float y1f = __builtin_amdgcn_fmed3f(yf0 + 1.0f, 0.f,  127.f);

        const float basef = fminf(x0f, 2046.0f);
        const int base_i = (int)basef;
        const int y0c    = (int)y0f;
        const int y1c    = (int)y1f;

        const f2v v0 = *(const f2v*)(img + y0c * W_ + base_i);
        const f2v v1 = *(const f2v*)(img + y1c * W_ + base_i);

        const bool hiA = (x0f == 2047.0f);   // right clamp
        const bool loC = (x1f == basef);     // left clamp
        const float Ia = hiA ? v0.y : v0.x;
        const float Ic = loC ? v0.x : v0.y;
        const float Ib = hiA ? v1.y : v1.x;
        const float Id = loC ? v1.x : v1.y;

        const float gx = x1f - xq;
        const float fx = xq - x0f;
        const float gy = y1f - yq;
        const float fy = yq - y0f;

        const float wa = gx * gy;
        const float wb = gx * fy;
        const float wc = fx * gy;
        const float wd = fx * fy;

        const float pa = wa * Ia;
        const float pb = wb * Ib;
        const float s1 = pa + pb;
        const float pc = wc * Ic;
        const float s2 = s1 + pc;
        const float pd = wd * Id;
        o[i] = s2 + pd;
    }

    const size_t oidx = ((size_t)b * OH_ + yo) * OW_ + xo0;
    __builtin_nontemporal_store(o, (nfloat4*)(out + oidx));
}

extern "C" void kernel_launch(void* const* d_in, const int* in_sizes, int n_in,
                              void* d_out, int out_size, void* d_ws, size_t ws_size,
                              hipStream_t stream)
{
    const float* x  = (const float*)d_in[0];
    const float* w  = (const float*)d_in[1];
    const float* bl = (const float*)d_in[2];
    float* out = (float*)d_out;

    // d_out doubles as the 1.26 MB block-sum scratch (820*384 floats), fully
    // consumed by st_theta_final before st_sample overwrites every element.
    float* part  = (float*)d_out;
    float* theta = (float*)d_ws;    // 384 floats

    st_block_sums<<<NBLK * 2, 192, 0, stream>>>(x, w, part);
    st_theta_final<<<6, 64, 0, stream>>>(part, bl, theta);
    st_sample<<<B_ * OH_ * 2, 256, 0, stream>>>(x, theta, out);
}